// Round 1
// baseline (2540.408 us; speedup 1.0000x reference)
//
#include <hip/hip_runtime.h>
#include <math.h>

#define N_NODES 100000
#define N_EDGES 3200000
#define IN_DIM  500
#define HID     64
#define OUT_DIM 40
#define K_ITERS 10
#define ALPHA   0.1f
#define BN_EPS  1e-5f

// ---------------- CSR build ----------------

__global__ void zero_cnt_kernel(int* __restrict__ cnt) {
    int i = blockIdx.x * 256 + threadIdx.x;
    if (i < N_NODES) cnt[i] = 0;
}

__global__ void hist_kernel(const int* __restrict__ ei, int* __restrict__ cnt) {
    int e = blockIdx.x * 256 + threadIdx.x;
    if (e < N_EDGES) atomicAdd(&cnt[ei[N_EDGES + e]], 1);  // col = ei[1][e]
}

__global__ void dinv_kernel(const int* __restrict__ cnt, float* __restrict__ dinv) {
    int i = blockIdx.x * 256 + threadIdx.x;
    if (i < N_NODES) dinv[i] = rsqrtf((float)(cnt[i] + 1));  // +1 self-loop; always > 0
}

// single-block exclusive scan of cnt -> rowptr[0..N], rowptr[N]=E
__global__ void scan_kernel(const int* __restrict__ cnt, int* __restrict__ rowptr) {
    __shared__ int sm[1024];
    __shared__ int srun;
    if (threadIdx.x == 0) srun = 0;
    for (int base = 0; base < N_NODES; base += 1024) {
        int i = base + threadIdx.x;
        int v = (i < N_NODES) ? cnt[i] : 0;
        __syncthreads();
        sm[threadIdx.x] = v;
        __syncthreads();
        for (int off = 1; off < 1024; off <<= 1) {
            int t = (threadIdx.x >= (unsigned)off) ? sm[threadIdx.x - off] : 0;
            __syncthreads();
            sm[threadIdx.x] += t;
            __syncthreads();
        }
        int excl = sm[threadIdx.x] - v;
        if (i < N_NODES) rowptr[i] = srun + excl;
        int tot = sm[1023];
        __syncthreads();
        if (threadIdx.x == 0) srun += tot;
    }
    __syncthreads();
    if (threadIdx.x == 0) rowptr[N_NODES] = srun;
}

__global__ void cursor_copy_kernel(const int* __restrict__ rowptr, int* __restrict__ cursor) {
    int i = blockIdx.x * 256 + threadIdx.x;
    if (i < N_NODES) cursor[i] = rowptr[i];
}

__global__ void fill_kernel(const int* __restrict__ ei, const float* __restrict__ dinv,
                            int* __restrict__ cursor, int* __restrict__ csr_idx,
                            float* __restrict__ csr_w) {
    int e = blockIdx.x * 256 + threadIdx.x;
    if (e < N_EDGES) {
        int r = ei[e];
        int c = ei[N_EDGES + e];
        int pos = atomicAdd(&cursor[c], 1);
        csr_idx[pos] = r;
        csr_w[pos] = dinv[r] * dinv[c];
    }
}

// ---------------- lin1: h = x @ W1 + b1 ----------------
// block = 256 (4 waves); each wave handles 8 nodes; W1 staged in LDS in K-chunks.
#define KC 100
__global__ __launch_bounds__(256) void lin1_kernel(const float* __restrict__ x,
                                                   const float* __restrict__ W1,
                                                   const float* __restrict__ b1,
                                                   float* __restrict__ h) {
    __shared__ float W1s[KC * HID];
    const int hid = threadIdx.x & 63;
    const int wv  = threadIdx.x >> 6;
    const int nbase = blockIdx.x * 32 + wv * 8;   // 3125 blocks * 32 = 100000 exactly
    float acc[8];
#pragma unroll
    for (int j = 0; j < 8; ++j) acc[j] = 0.0f;

    for (int k0 = 0; k0 < IN_DIM; k0 += KC) {
        __syncthreads();
        for (int i = threadIdx.x; i < KC * HID; i += 256) W1s[i] = W1[k0 * HID + i];
        __syncthreads();
        for (int kk = 0; kk < KC; kk += 4) {
            float w0 = W1s[(kk + 0) * HID + hid];
            float w1 = W1s[(kk + 1) * HID + hid];
            float w2 = W1s[(kk + 2) * HID + hid];
            float w3 = W1s[(kk + 3) * HID + hid];
#pragma unroll
            for (int j = 0; j < 8; ++j) {
                const float4 xv = *(const float4*)(x + (size_t)(nbase + j) * IN_DIM + k0 + kk);
                acc[j] = fmaf(xv.x, w0, fmaf(xv.y, w1, fmaf(xv.z, w2, fmaf(xv.w, w3, acc[j]))));
            }
        }
    }
    float bb = b1[hid];
#pragma unroll
    for (int j = 0; j < 8; ++j) h[(size_t)(nbase + j) * HID + hid] = acc[j] + bb;
}

// ---------------- APPNP step ----------------
// 16 lanes per node (float4 over 64 feats); block 256 = 16 nodes.
__global__ __launch_bounds__(256) void appnp_step_kernel(const int* __restrict__ rowptr,
                                                         const int* __restrict__ csr_idx,
                                                         const float* __restrict__ csr_w,
                                                         const float* __restrict__ dinv,
                                                         const float* __restrict__ xin,
                                                         const float* __restrict__ h,
                                                         float* __restrict__ xout) {
    const int sub   = threadIdx.x >> 4;          // 0..15
    const int lane4 = threadIdx.x & 15;          // float4 index within 64 feats
    const int node  = blockIdx.x * 16 + sub;     // 6250 * 16 = 100000 exactly

    const int beg = rowptr[node];
    const int end = rowptr[node + 1];
    float4 acc = make_float4(0.f, 0.f, 0.f, 0.f);
    for (int p = beg; p < end; ++p) {
        const int r = csr_idx[p];
        const float w = csr_w[p];
        const float4 xr = *(const float4*)(xin + (size_t)r * HID + lane4 * 4);
        acc.x = fmaf(w, xr.x, acc.x);
        acc.y = fmaf(w, xr.y, acc.y);
        acc.z = fmaf(w, xr.z, acc.z);
        acc.w = fmaf(w, xr.w, acc.w);
    }
    const float di = dinv[node];
    const float selfw = di * di;
    const float4 xs = *(const float4*)(xin + (size_t)node * HID + lane4 * 4);
    const float4 hh = *(const float4*)(h + (size_t)node * HID + lane4 * 4);
    float4 out;
    out.x = (1.0f - ALPHA) * fmaf(selfw, xs.x, acc.x) + ALPHA * hh.x;
    out.y = (1.0f - ALPHA) * fmaf(selfw, xs.y, acc.y) + ALPHA * hh.y;
    out.z = (1.0f - ALPHA) * fmaf(selfw, xs.z, acc.z) + ALPHA * hh.z;
    out.w = (1.0f - ALPHA) * fmaf(selfw, xs.w, acc.w) + ALPHA * hh.w;
    *(float4*)(xout + (size_t)node * HID + lane4 * 4) = out;
}

// ---------------- BN + lin2 + log_softmax, write both outputs ----------------
// block 256 = 4 waves, one node per wave.
__global__ __launch_bounds__(256) void final_kernel(const float* __restrict__ xk,
                                                    const float* __restrict__ gamma,
                                                    const float* __restrict__ beta,
                                                    const float* __restrict__ mean,
                                                    const float* __restrict__ var,
                                                    const float* __restrict__ W2,
                                                    const float* __restrict__ b2,
                                                    float* __restrict__ out_ls,
                                                    float* __restrict__ out_emb) {
    __shared__ float sh[256];
    const int lane = threadIdx.x & 63;
    const int wv   = threadIdx.x >> 6;
    const int node = blockIdx.x * 4 + wv;        // 25000 * 4 = 100000 exactly

    float xv = xk[(size_t)node * HID + lane];
    float hbn = (xv - mean[lane]) * rsqrtf(var[lane] + BN_EPS) * gamma[lane] + beta[lane];
    sh[threadIdx.x] = hbn;
    __syncthreads();

    float e = 0.0f;
    if (lane < OUT_DIM) {
        e = b2[lane];
        const float* shw = sh + wv * 64;
#pragma unroll
        for (int hh = 0; hh < HID; ++hh) e = fmaf(shw[hh], W2[hh * OUT_DIM + lane], e);
    }
    float ev = (lane < OUT_DIM) ? e : -INFINITY;
    float m = ev;
#pragma unroll
    for (int off = 32; off > 0; off >>= 1) m = fmaxf(m, __shfl_xor(m, off, 64));
    float p = (lane < OUT_DIM) ? expf(ev - m) : 0.0f;
    float s = p;
#pragma unroll
    for (int off = 32; off > 0; off >>= 1) s += __shfl_xor(s, off, 64);
    if (lane < OUT_DIM) {
        float ls = ev - m - logf(s);
        out_ls[(size_t)node * OUT_DIM + lane] = ls;
        out_emb[(size_t)node * OUT_DIM + lane] = e;
    }
}

// ---------------- launch ----------------

extern "C" void kernel_launch(void* const* d_in, const int* in_sizes, int n_in,
                              void* d_out, int out_size, void* d_ws, size_t ws_size,
                              hipStream_t stream) {
    const float* x     = (const float*)d_in[0];
    const int*   ei    = (const int*)d_in[1];     // [2, E] int32
    const float* W1    = (const float*)d_in[2];
    const float* b1    = (const float*)d_in[3];
    const float* gamma = (const float*)d_in[4];
    const float* beta  = (const float*)d_in[5];
    const float* mean  = (const float*)d_in[6];
    const float* var   = (const float*)d_in[7];
    const float* W2    = (const float*)d_in[8];
    const float* b2    = (const float*)d_in[9];

    char* ws = (char*)d_ws;
    const size_t SZ_X = (size_t)N_NODES * HID * sizeof(float);   // 25.6 MB
    float* h       = (float*)(ws);
    float* xa      = (float*)(ws + SZ_X);
    float* xb      = (float*)(ws + 2 * SZ_X);
    int*   csr_idx = (int*)  (ws + 3 * SZ_X);
    float* csr_w   = (float*)(ws + 3 * SZ_X + (size_t)N_EDGES * 4);
    int*   cnt     = (int*)  (ws + 3 * SZ_X + (size_t)N_EDGES * 8);
    float* dinv    = (float*)(ws + 3 * SZ_X + (size_t)N_EDGES * 8 + 400000);
    int*   rowptr  = (int*)  (ws + 3 * SZ_X + (size_t)N_EDGES * 8 + 800000);
    int*   cursor  = (int*)  (ws + 3 * SZ_X + (size_t)N_EDGES * 8 + 1200016);

    float* out_ls  = (float*)d_out;
    float* out_emb = (float*)d_out + (size_t)N_NODES * OUT_DIM;

    const int NB_N = (N_NODES + 255) / 256;   // 391
    const int NB_E = (N_EDGES + 255) / 256;   // 12500

    zero_cnt_kernel<<<NB_N, 256, 0, stream>>>(cnt);
    hist_kernel<<<NB_E, 256, 0, stream>>>(ei, cnt);
    dinv_kernel<<<NB_N, 256, 0, stream>>>(cnt, dinv);
    scan_kernel<<<1, 1024, 0, stream>>>(cnt, rowptr);
    cursor_copy_kernel<<<NB_N, 256, 0, stream>>>(rowptr, cursor);
    fill_kernel<<<NB_E, 256, 0, stream>>>(ei, dinv, cursor, csr_idx, csr_w);

    lin1_kernel<<<N_NODES / 32, 256, 0, stream>>>(x, W1, b1, h);

    // K=10 APPNP steps, ping-pong: h -> xa -> xb -> ... -> xb (ends in xb)
    const float* cur = h;
    float* nxt = xa;
    float* buf[2] = {xa, xb};
    for (int k = 0; k < K_ITERS; ++k) {
        appnp_step_kernel<<<N_NODES / 16, 256, 0, stream>>>(rowptr, csr_idx, csr_w, dinv,
                                                            cur, h, nxt);
        cur = nxt;
        nxt = buf[(k + 1) & 1];
    }

    final_kernel<<<N_NODES / 4, 256, 0, stream>>>(cur, gamma, beta, mean, var, W2, b2,
                                                  out_ls, out_emb);
}

// Round 2
// 1858.441 us; speedup vs baseline: 1.3670x; 1.3670x over previous
//
#include <hip/hip_runtime.h>
#include <math.h>

#define N_NODES 100000
#define N_EDGES 3200000
#define IN_DIM  500
#define HID     64
#define OUT_DIM 40
#define K_ITERS 10
#define ALPHA   0.1f
#define BN_EPS  1e-5f

// ---------------- CSR build ----------------

__global__ void zero_cnt_kernel(int* __restrict__ cnt) {
    int i = blockIdx.x * 256 + threadIdx.x;
    if (i < N_NODES) cnt[i] = 0;
}

__global__ void hist_kernel(const int* __restrict__ ei, int* __restrict__ cnt) {
    int e = blockIdx.x * 256 + threadIdx.x;
    if (e < N_EDGES) atomicAdd(&cnt[ei[N_EDGES + e]], 1);  // col = ei[1][e]
}

// 391 blocks x 256: per-block sum of cnt
__global__ void reduce_kernel(const int* __restrict__ cnt, int* __restrict__ psum) {
    __shared__ int s[256];
    int i = blockIdx.x * 256 + threadIdx.x;
    int v = (i < N_NODES) ? cnt[i] : 0;
    s[threadIdx.x] = v;
    __syncthreads();
    for (int off = 128; off > 0; off >>= 1) {
        if (threadIdx.x < (unsigned)off) s[threadIdx.x] += s[threadIdx.x + off];
        __syncthreads();
    }
    if (threadIdx.x == 0) psum[blockIdx.x] = s[0];
}

// 1 block x 512: exclusive scan of 391 partials
__global__ void scanp_kernel(const int* __restrict__ psum, int* __restrict__ pexcl,
                             int nparts) {
    __shared__ int s[512];
    int t = threadIdx.x;
    int v = (t < nparts) ? psum[t] : 0;
    s[t] = v;
    __syncthreads();
    for (int off = 1; off < 512; off <<= 1) {
        int tv = (t >= off) ? s[t - off] : 0;
        __syncthreads();
        s[t] += tv;
        __syncthreads();
    }
    if (t < nparts) pexcl[t] = s[t] - v;
}

// 391 blocks x 256: block-local exclusive scan + partial offset -> rowptr/cursor; dinv fused
__global__ void apply_kernel(const int* __restrict__ cnt, const int* __restrict__ pexcl,
                             int* __restrict__ rowptr, int* __restrict__ cursor,
                             float* __restrict__ dinv) {
    __shared__ int s[256];
    int t = threadIdx.x;
    int i = blockIdx.x * 256 + t;
    int v = (i < N_NODES) ? cnt[i] : 0;
    s[t] = v;
    __syncthreads();
    for (int off = 1; off < 256; off <<= 1) {
        int tv = (t >= off) ? s[t - off] : 0;
        __syncthreads();
        s[t] += tv;
        __syncthreads();
    }
    if (i < N_NODES) {
        int excl = pexcl[blockIdx.x] + s[t] - v;
        rowptr[i] = excl;
        cursor[i] = excl;
        dinv[i] = rsqrtf((float)(v + 1));        // +1 self-loop; always > 0
        if (i == N_NODES - 1) rowptr[N_NODES] = excl + v;
    }
}

// pack (src, w) per edge into int2
__global__ void fill_kernel(const int* __restrict__ ei, const float* __restrict__ dinv,
                            int* __restrict__ cursor, int2* __restrict__ ew) {
    int e = blockIdx.x * 256 + threadIdx.x;
    if (e < N_EDGES) {
        int r = ei[e];
        int c = ei[N_EDGES + e];
        int pos = atomicAdd(&cursor[c], 1);
        ew[pos] = make_int2(r, __float_as_int(dinv[r] * dinv[c]));
    }
}

// ---------------- lin1: h = x @ W1 + b1 ----------------
// Tiled GEMM: M-tile 128 nodes, KC=20, block 256.
// LDS: xsT[k][132] (transposed, pitch 132: 16B-aligned b128 reads, <=2-way write conflicts),
//      W1s[k][64]. Each thread: 4 nodes x 8 hid = 32 acc; per k: 3x ds_read_b128 + 32 FMA.
#define L1_M  128
#define L1_KC 20
#define L1_PITCH 132
__global__ __launch_bounds__(256) void lin1_kernel(const float* __restrict__ x,
                                                   const float* __restrict__ W1,
                                                   const float* __restrict__ b1,
                                                   float* __restrict__ h) {
    __shared__ float xsT[L1_KC * L1_PITCH];   // [k][node], 10560 B
    __shared__ float W1s[L1_KC * HID];        // [k][hid], 5120 B

    const int t = threadIdx.x;
    const int ng = t & 31;                    // node group: nodes ng*4 .. +3
    const int hg = t >> 5;                    // hid group: hids hg*8 .. +7
    const int nbase = blockIdx.x * L1_M;

    // staging assignment for x: row = t>>1 (0..127), kb = (t&1)*10
    const int srow = t >> 1;
    const int skb  = (t & 1) * 10;
    const int gsrc = nbase + srow;
    const int gclamped = (gsrc < N_NODES) ? gsrc : (N_NODES - 1);
    const float* xrow = x + (size_t)gclamped * IN_DIM;

    float acc[4][8];
#pragma unroll
    for (int i = 0; i < 4; ++i)
#pragma unroll
        for (int j = 0; j < 8; ++j) acc[i][j] = 0.0f;

    for (int k0 = 0; k0 < IN_DIM; k0 += L1_KC) {
        __syncthreads();
        // stage x chunk (transposed): 5 float2 loads per thread
#pragma unroll
        for (int u = 0; u < 5; ++u) {
            const float2 xv = *(const float2*)(xrow + k0 + skb + 2 * u);
            xsT[(skb + 2 * u) * L1_PITCH + srow]     = xv.x;
            xsT[(skb + 2 * u + 1) * L1_PITCH + srow] = xv.y;
        }
        // stage W1 chunk: 5 scalar coalesced loads per thread
#pragma unroll
        for (int u = 0; u < 5; ++u) {
            int i = t + u * 256;                        // 0..1279
            W1s[i] = W1[(size_t)k0 * HID + i];
        }
        __syncthreads();

#pragma unroll 4
        for (int k = 0; k < L1_KC; ++k) {
            const float4 xv = *(const float4*)&xsT[k * L1_PITCH + ng * 4];
            const float4 w0 = *(const float4*)&W1s[k * HID + hg * 8];
            const float4 w1 = *(const float4*)&W1s[k * HID + hg * 8 + 4];
            const float xr[4] = {xv.x, xv.y, xv.z, xv.w};
            const float wr[8] = {w0.x, w0.y, w0.z, w0.w, w1.x, w1.y, w1.z, w1.w};
#pragma unroll
            for (int i = 0; i < 4; ++i)
#pragma unroll
                for (int j = 0; j < 8; ++j)
                    acc[i][j] = fmaf(xr[i], wr[j], acc[i][j]);
        }
    }

    // epilogue: + b1, store
    float bb[8];
#pragma unroll
    for (int j = 0; j < 8; ++j) bb[j] = b1[hg * 8 + j];
#pragma unroll
    for (int i = 0; i < 4; ++i) {
        const int n = nbase + ng * 4 + i;
        if (n < N_NODES) {
            float4 o0 = make_float4(acc[i][0] + bb[0], acc[i][1] + bb[1],
                                    acc[i][2] + bb[2], acc[i][3] + bb[3]);
            float4 o1 = make_float4(acc[i][4] + bb[4], acc[i][5] + bb[5],
                                    acc[i][6] + bb[6], acc[i][7] + bb[7]);
            *(float4*)(h + (size_t)n * HID + hg * 8)     = o0;
            *(float4*)(h + (size_t)n * HID + hg * 8 + 4) = o1;
        }
    }
}

// ---------------- APPNP step ----------------
// 16 lanes per node (float4 over 64 feats); block 256 = 16 nodes.
__global__ __launch_bounds__(256) void appnp_step_kernel(const int* __restrict__ rowptr,
                                                         const int2* __restrict__ ew,
                                                         const float* __restrict__ dinv,
                                                         const float* __restrict__ xin,
                                                         const float* __restrict__ h,
                                                         float* __restrict__ xout) {
    const int sub   = threadIdx.x >> 4;          // 0..15
    const int lane4 = threadIdx.x & 15;          // float4 index within 64 feats
    const int node  = blockIdx.x * 16 + sub;     // 6250 * 16 = 100000 exactly

    const int beg = rowptr[node];
    const int end = rowptr[node + 1];
    float4 acc = make_float4(0.f, 0.f, 0.f, 0.f);
    int p = beg;
    for (; p + 1 < end; p += 2) {
        const int2 e0 = ew[p];
        const int2 e1 = ew[p + 1];
        const float w0 = __int_as_float(e0.y);
        const float w1 = __int_as_float(e1.y);
        const float4 x0 = *(const float4*)(xin + (size_t)e0.x * HID + lane4 * 4);
        const float4 x1 = *(const float4*)(xin + (size_t)e1.x * HID + lane4 * 4);
        acc.x = fmaf(w0, x0.x, acc.x); acc.y = fmaf(w0, x0.y, acc.y);
        acc.z = fmaf(w0, x0.z, acc.z); acc.w = fmaf(w0, x0.w, acc.w);
        acc.x = fmaf(w1, x1.x, acc.x); acc.y = fmaf(w1, x1.y, acc.y);
        acc.z = fmaf(w1, x1.z, acc.z); acc.w = fmaf(w1, x1.w, acc.w);
    }
    if (p < end) {
        const int2 e0 = ew[p];
        const float w0 = __int_as_float(e0.y);
        const float4 x0 = *(const float4*)(xin + (size_t)e0.x * HID + lane4 * 4);
        acc.x = fmaf(w0, x0.x, acc.x); acc.y = fmaf(w0, x0.y, acc.y);
        acc.z = fmaf(w0, x0.z, acc.z); acc.w = fmaf(w0, x0.w, acc.w);
    }
    const float di = dinv[node];
    const float selfw = di * di;
    const float4 xs = *(const float4*)(xin + (size_t)node * HID + lane4 * 4);
    const float4 hh = *(const float4*)(h + (size_t)node * HID + lane4 * 4);
    float4 out;
    out.x = (1.0f - ALPHA) * fmaf(selfw, xs.x, acc.x) + ALPHA * hh.x;
    out.y = (1.0f - ALPHA) * fmaf(selfw, xs.y, acc.y) + ALPHA * hh.y;
    out.z = (1.0f - ALPHA) * fmaf(selfw, xs.z, acc.z) + ALPHA * hh.z;
    out.w = (1.0f - ALPHA) * fmaf(selfw, xs.w, acc.w) + ALPHA * hh.w;
    *(float4*)(xout + (size_t)node * HID + lane4 * 4) = out;
}

// ---------------- BN + lin2 + log_softmax, write both outputs ----------------
// block 256 = 4 waves, one node per wave.
__global__ __launch_bounds__(256) void final_kernel(const float* __restrict__ xk,
                                                    const float* __restrict__ gamma,
                                                    const float* __restrict__ beta,
                                                    const float* __restrict__ mean,
                                                    const float* __restrict__ var,
                                                    const float* __restrict__ W2,
                                                    const float* __restrict__ b2,
                                                    float* __restrict__ out_ls,
                                                    float* __restrict__ out_emb) {
    __shared__ float sh[256];
    const int lane = threadIdx.x & 63;
    const int wv   = threadIdx.x >> 6;
    const int node = blockIdx.x * 4 + wv;        // 25000 * 4 = 100000 exactly

    float xv = xk[(size_t)node * HID + lane];
    float hbn = (xv - mean[lane]) * rsqrtf(var[lane] + BN_EPS) * gamma[lane] + beta[lane];
    sh[threadIdx.x] = hbn;
    __syncthreads();

    float e = 0.0f;
    if (lane < OUT_DIM) {
        e = b2[lane];
        const float* shw = sh + wv * 64;
#pragma unroll
        for (int hh = 0; hh < HID; ++hh) e = fmaf(shw[hh], W2[hh * OUT_DIM + lane], e);
    }
    float ev = (lane < OUT_DIM) ? e : -INFINITY;
    float m = ev;
#pragma unroll
    for (int off = 32; off > 0; off >>= 1) m = fmaxf(m, __shfl_xor(m, off, 64));
    float p = (lane < OUT_DIM) ? expf(ev - m) : 0.0f;
    float s = p;
#pragma unroll
    for (int off = 32; off > 0; off >>= 1) s += __shfl_xor(s, off, 64);
    if (lane < OUT_DIM) {
        float ls = ev - m - logf(s);
        out_ls[(size_t)node * OUT_DIM + lane] = ls;
        out_emb[(size_t)node * OUT_DIM + lane] = e;
    }
}

// ---------------- launch ----------------

extern "C" void kernel_launch(void* const* d_in, const int* in_sizes, int n_in,
                              void* d_out, int out_size, void* d_ws, size_t ws_size,
                              hipStream_t stream) {
    const float* x     = (const float*)d_in[0];
    const int*   ei    = (const int*)d_in[1];     // [2, E] int32
    const float* W1    = (const float*)d_in[2];
    const float* b1    = (const float*)d_in[3];
    const float* gamma = (const float*)d_in[4];
    const float* beta  = (const float*)d_in[5];
    const float* mean  = (const float*)d_in[6];
    const float* var   = (const float*)d_in[7];
    const float* W2    = (const float*)d_in[8];
    const float* b2    = (const float*)d_in[9];

    char* ws = (char*)d_ws;
    const size_t SZ_X = (size_t)N_NODES * HID * sizeof(float);   // 25.6 MB
    float* h      = (float*)(ws);
    float* xa     = (float*)(ws + SZ_X);
    float* xb     = (float*)(ws + 2 * SZ_X);
    int2*  ew     = (int2*) (ws + 3 * SZ_X);                      // 25.6 MB
    char*  base2  = ws + 3 * SZ_X + (size_t)N_EDGES * 8;
    int*   cnt    = (int*)  (base2);
    float* dinv   = (float*)(base2 + 400000);
    int*   rowptr = (int*)  (base2 + 800000);
    int*   cursor = (int*)  (base2 + 1200016);
    int*   psum   = (int*)  (base2 + 1600016);
    int*   pexcl  = (int*)  (base2 + 1604016);

    float* out_ls  = (float*)d_out;
    float* out_emb = (float*)d_out + (size_t)N_NODES * OUT_DIM;

    const int NB_N = (N_NODES + 255) / 256;   // 391
    const int NB_E = (N_EDGES + 255) / 256;   // 12500

    zero_cnt_kernel<<<NB_N, 256, 0, stream>>>(cnt);
    hist_kernel<<<NB_E, 256, 0, stream>>>(ei, cnt);
    reduce_kernel<<<NB_N, 256, 0, stream>>>(cnt, psum);
    scanp_kernel<<<1, 512, 0, stream>>>(psum, pexcl, NB_N);
    apply_kernel<<<NB_N, 256, 0, stream>>>(cnt, pexcl, rowptr, cursor, dinv);
    fill_kernel<<<NB_E, 256, 0, stream>>>(ei, dinv, cursor, ew);

    lin1_kernel<<<(N_NODES + L1_M - 1) / L1_M, 256, 0, stream>>>(x, W1, b1, h);

    // K=10 APPNP steps, ping-pong
    const float* cur = h;
    float* nxt = xa;
    float* buf[2] = {xa, xb};
    for (int k = 0; k < K_ITERS; ++k) {
        appnp_step_kernel<<<N_NODES / 16, 256, 0, stream>>>(rowptr, ew, dinv, cur, h, nxt);
        cur = nxt;
        nxt = buf[(k + 1) & 1];
    }

    final_kernel<<<N_NODES / 4, 256, 0, stream>>>(cur, gamma, beta, mean, var, W2, b2,
                                                  out_ls, out_emb);
}

// Round 3
// 1501.657 us; speedup vs baseline: 1.6917x; 1.2376x over previous
//
#include <hip/hip_runtime.h>
#include <math.h>

#define N_NODES 100000
#define N_EDGES 3200000
#define IN_DIM  500
#define HID     64
#define OUT_DIM 40
#define K_ITERS 10
#define ALPHA   0.1f
#define BN_EPS  1e-5f

#define PDIM 48   // padded propagation dim (fp32 stride 48 floats = 192B; bf16 stride 48 = 96B)

// ---------------- bf16 helpers ----------------
__device__ __forceinline__ void unpack4(uint2 v, float f[4]) {
    f[0] = __uint_as_float(v.x << 16);
    f[1] = __uint_as_float(v.x & 0xffff0000u);
    f[2] = __uint_as_float(v.y << 16);
    f[3] = __uint_as_float(v.y & 0xffff0000u);
}
__device__ __forceinline__ unsigned pack2(float a, float b) {   // RNE bf16 pair
    unsigned ua = __float_as_uint(a);
    unsigned ub = __float_as_uint(b);
    ua += ((ua >> 16) & 1u) + 0x7fffu;
    ub += ((ub >> 16) & 1u) + 0x7fffu;
    return (ua >> 16) | (ub & 0xffff0000u);
}

// ---------------- CSR build ----------------

__global__ void zero_cnt_kernel(int* __restrict__ cnt) {
    int i = blockIdx.x * 256 + threadIdx.x;
    if (i < N_NODES) cnt[i] = 0;
}

__global__ void hist_kernel(const int* __restrict__ ei, int* __restrict__ cnt) {
    int e = blockIdx.x * 256 + threadIdx.x;
    if (e < N_EDGES) atomicAdd(&cnt[ei[N_EDGES + e]], 1);  // col = ei[1][e]
}

__global__ void reduce_kernel(const int* __restrict__ cnt, int* __restrict__ psum) {
    __shared__ int s[256];
    int i = blockIdx.x * 256 + threadIdx.x;
    int v = (i < N_NODES) ? cnt[i] : 0;
    s[threadIdx.x] = v;
    __syncthreads();
    for (int off = 128; off > 0; off >>= 1) {
        if (threadIdx.x < (unsigned)off) s[threadIdx.x] += s[threadIdx.x + off];
        __syncthreads();
    }
    if (threadIdx.x == 0) psum[blockIdx.x] = s[0];
}

__global__ void scanp_kernel(const int* __restrict__ psum, int* __restrict__ pexcl,
                             int nparts) {
    __shared__ int s[512];
    int t = threadIdx.x;
    int v = (t < nparts) ? psum[t] : 0;
    s[t] = v;
    __syncthreads();
    for (int off = 1; off < 512; off <<= 1) {
        int tv = (t >= off) ? s[t - off] : 0;
        __syncthreads();
        s[t] += tv;
        __syncthreads();
    }
    if (t < nparts) pexcl[t] = s[t] - v;
}

__global__ void apply_kernel(const int* __restrict__ cnt, const int* __restrict__ pexcl,
                             int* __restrict__ rowptr, int* __restrict__ cursor,
                             float* __restrict__ dinv) {
    __shared__ int s[256];
    int t = threadIdx.x;
    int i = blockIdx.x * 256 + t;
    int v = (i < N_NODES) ? cnt[i] : 0;
    s[t] = v;
    __syncthreads();
    for (int off = 1; off < 256; off <<= 1) {
        int tv = (t >= off) ? s[t - off] : 0;
        __syncthreads();
        s[t] += tv;
        __syncthreads();
    }
    if (i < N_NODES) {
        int excl = pexcl[blockIdx.x] + s[t] - v;
        rowptr[i] = excl;
        cursor[i] = excl;
        dinv[i] = rsqrtf((float)(v + 1));        // +1 self-loop; always > 0
        if (i == N_NODES - 1) rowptr[N_NODES] = excl + v;
    }
}

__global__ void fill_kernel(const int* __restrict__ ei, const float* __restrict__ dinv,
                            int* __restrict__ cursor, int2* __restrict__ ew) {
    int e = blockIdx.x * 256 + threadIdx.x;
    if (e < N_EDGES) {
        int r = ei[e];
        int c = ei[N_EDGES + e];
        int pos = atomicAdd(&cursor[c], 1);
        ew[pos] = make_int2(r, __float_as_int(dinv[r] * dinv[c]));
    }
}

// ---------------- fold BN+W2 into propagation space ----------------
// W2p[f][o] = s[f]*g[f]*W2[f][o];  cbeta[o] = sum_f (beta[f]-m[f]*s[f]*g[f])*W2[f][o] + b2[o]
// c1[o] = sum_f b1[f]*W2p[f][o]
__global__ void prep_kernel(const float* __restrict__ W2, const float* __restrict__ gamma,
                            const float* __restrict__ beta, const float* __restrict__ mean,
                            const float* __restrict__ var, const float* __restrict__ b1,
                            const float* __restrict__ b2, float* __restrict__ W2p,
                            float* __restrict__ c1, float* __restrict__ cbeta) {
    __shared__ float sc[64];
    __shared__ float sd[64];
    int t = threadIdx.x;
    if (t < 64) {
        float s = rsqrtf(var[t] + BN_EPS) * gamma[t];
        sc[t] = s;
        sd[t] = beta[t] - mean[t] * s;
    }
    __syncthreads();
    for (int i = t; i < 64 * OUT_DIM; i += 256) {
        int f = i / OUT_DIM;
        W2p[i] = sc[f] * W2[i];
    }
    if (t < PDIM) {
        if (t < OUT_DIM) {
            float acb = b2[t], ac1 = 0.f;
            for (int f = 0; f < 64; ++f) {
                float w2 = W2[f * OUT_DIM + t];
                acb = fmaf(sd[f], w2, acb);
                ac1 = fmaf(b1[f] * sc[f], w2, ac1);
            }
            cbeta[t] = acb;
            c1[t] = ac1;
        } else {
            c1[t] = 0.f;
        }
    }
}

// Wc[k][o] (500 x 48, pad zero) = sum_f W1[k][f] * W2p[f][o]
__global__ __launch_bounds__(256) void wc_kernel(const float* __restrict__ W1,
                                                 const float* __restrict__ W2p,
                                                 float* __restrict__ Wc) {
    __shared__ float w2s[64 * OUT_DIM];
    for (int i = threadIdx.x; i < 64 * OUT_DIM; i += 256) w2s[i] = W2p[i];
    __syncthreads();
    int idx = blockIdx.x * 256 + threadIdx.x;
    if (idx >= IN_DIM * PDIM) return;
    int k = idx / PDIM, o = idx % PDIM;
    float a = 0.f;
    if (o < OUT_DIM) {
        const float* w1r = W1 + (size_t)k * HID;
#pragma unroll 8
        for (int f = 0; f < 64; ++f) a = fmaf(w1r[f], w2s[f * OUT_DIM + o], a);
    }
    Wc[idx] = a;
}

// ---------------- y0 = x @ Wc + c1 ----------------
// M-tile 128, KC=20; LDS xsT transposed (pitch 132); writes fp32 (teleport) + bf16 (gather).
#define L1_M  128
#define L1_KC 20
#define L1_PITCH 132
__global__ __launch_bounds__(256) void lin1_kernel(const float* __restrict__ x,
                                                   const float* __restrict__ Wc,
                                                   const float* __restrict__ c1,
                                                   float* __restrict__ y0f,
                                                   unsigned* __restrict__ y0b) {
    __shared__ float xsT[L1_KC * L1_PITCH];
    __shared__ float wcs[L1_KC * PDIM];

    const int t = threadIdx.x;
    const int ng = t & 31;                    // 4 nodes each
    const int og = t >> 5;                    // 8 groups x 6 outs
    const int nbase = blockIdx.x * L1_M;

    const int srow = t >> 1;
    const int skb  = (t & 1) * 10;
    const int gsrc = nbase + srow;
    const int gcl  = (gsrc < N_NODES) ? gsrc : (N_NODES - 1);
    const float* xrow = x + (size_t)gcl * IN_DIM;

    float acc[4][6];
#pragma unroll
    for (int i = 0; i < 4; ++i)
#pragma unroll
        for (int j = 0; j < 6; ++j) acc[i][j] = 0.0f;

    for (int k0 = 0; k0 < IN_DIM; k0 += L1_KC) {
        __syncthreads();
#pragma unroll
        for (int u = 0; u < 5; ++u) {
            const float2 xv = *(const float2*)(xrow + k0 + skb + 2 * u);
            xsT[(skb + 2 * u) * L1_PITCH + srow]     = xv.x;
            xsT[(skb + 2 * u + 1) * L1_PITCH + srow] = xv.y;
        }
        for (int i = t; i < L1_KC * PDIM; i += 256) wcs[i] = Wc[(size_t)k0 * PDIM + i];
        __syncthreads();

#pragma unroll 4
        for (int k = 0; k < L1_KC; ++k) {
            const float4 xv = *(const float4*)&xsT[k * L1_PITCH + ng * 4];
            float w[6];
#pragma unroll
            for (int j = 0; j < 6; ++j) w[j] = wcs[k * PDIM + og * 6 + j];
            const float xr[4] = {xv.x, xv.y, xv.z, xv.w};
#pragma unroll
            for (int i = 0; i < 4; ++i)
#pragma unroll
                for (int j = 0; j < 6; ++j)
                    acc[i][j] = fmaf(xr[i], w[j], acc[i][j]);
        }
    }

    float cc[6];
#pragma unroll
    for (int j = 0; j < 6; ++j) cc[j] = c1[og * 6 + j];
#pragma unroll
    for (int i = 0; i < 4; ++i) {
        const int n = nbase + ng * 4 + i;
        if (n < N_NODES) {
            float o[6];
#pragma unroll
            for (int j = 0; j < 6; ++j) o[j] = acc[i][j] + cc[j];
            float* yf = y0f + (size_t)n * PDIM + og * 6;
            *(float2*)(yf)     = make_float2(o[0], o[1]);
            *(float2*)(yf + 2) = make_float2(o[2], o[3]);
            *(float2*)(yf + 4) = make_float2(o[4], o[5]);
            unsigned* yb = y0b + (size_t)n * (PDIM / 2) + og * 3;
            yb[0] = pack2(o[0], o[1]);
            yb[1] = pack2(o[2], o[3]);
            yb[2] = pack2(o[4], o[5]);
        }
    }
}

// ---------------- APPNP step (40-dim, bf16 gather, fp32 accumulate) ----------------
// 16 lanes/node (10 active: 4 feats each); block 256 = 16 nodes.
template <bool LAST>
__global__ __launch_bounds__(256) void appnp40_kernel(const int* __restrict__ rowptr,
                                                      const int2* __restrict__ ew,
                                                      const float* __restrict__ dinv,
                                                      const unsigned* __restrict__ yin,
                                                      const float* __restrict__ h,
                                                      unsigned* __restrict__ yout,
                                                      float* __restrict__ yKf) {
    const int sub   = threadIdx.x >> 4;
    const int lane4 = threadIdx.x & 15;
    const int node  = blockIdx.x * 16 + sub;     // 6250 * 16 = 100000 exactly
    const bool act  = lane4 < 10;

    const int beg = rowptr[node];
    const int end = rowptr[node + 1];
    float4 acc = make_float4(0.f, 0.f, 0.f, 0.f);
    int p = beg;
    for (; p + 1 < end; p += 2) {
        const int2 e0 = ew[p];
        const int2 e1 = ew[p + 1];
        const float w0 = __int_as_float(e0.y);
        const float w1 = __int_as_float(e1.y);
        if (act) {
            const uint2 v0 = *(const uint2*)(yin + (size_t)e0.x * (PDIM / 2) + lane4 * 2);
            const uint2 v1 = *(const uint2*)(yin + (size_t)e1.x * (PDIM / 2) + lane4 * 2);
            float f0[4], f1[4];
            unpack4(v0, f0);
            unpack4(v1, f1);
            acc.x = fmaf(w0, f0[0], acc.x); acc.y = fmaf(w0, f0[1], acc.y);
            acc.z = fmaf(w0, f0[2], acc.z); acc.w = fmaf(w0, f0[3], acc.w);
            acc.x = fmaf(w1, f1[0], acc.x); acc.y = fmaf(w1, f1[1], acc.y);
            acc.z = fmaf(w1, f1[2], acc.z); acc.w = fmaf(w1, f1[3], acc.w);
        }
    }
    if (p < end) {
        const int2 e0 = ew[p];
        const float w0 = __int_as_float(e0.y);
        if (act) {
            const uint2 v0 = *(const uint2*)(yin + (size_t)e0.x * (PDIM / 2) + lane4 * 2);
            float f0[4];
            unpack4(v0, f0);
            acc.x = fmaf(w0, f0[0], acc.x); acc.y = fmaf(w0, f0[1], acc.y);
            acc.z = fmaf(w0, f0[2], acc.z); acc.w = fmaf(w0, f0[3], acc.w);
        }
    }
    if (act) {
        const float di = dinv[node];
        const float selfw = di * di;
        const uint2 vs = *(const uint2*)(yin + (size_t)node * (PDIM / 2) + lane4 * 2);
        float fs[4];
        unpack4(vs, fs);
        const float4 hh = *(const float4*)(h + (size_t)node * PDIM + lane4 * 4);
        float4 o;
        o.x = (1.0f - ALPHA) * fmaf(selfw, fs[0], acc.x) + ALPHA * hh.x;
        o.y = (1.0f - ALPHA) * fmaf(selfw, fs[1], acc.y) + ALPHA * hh.y;
        o.z = (1.0f - ALPHA) * fmaf(selfw, fs[2], acc.z) + ALPHA * hh.z;
        o.w = (1.0f - ALPHA) * fmaf(selfw, fs[3], acc.w) + ALPHA * hh.w;
        if (LAST) {
            *(float4*)(yKf + (size_t)node * PDIM + lane4 * 4) = o;
        } else {
            uint2 w;
            w.x = pack2(o.x, o.y);
            w.y = pack2(o.z, o.w);
            *(uint2*)(yout + (size_t)node * (PDIM / 2) + lane4 * 2) = w;
        }
    }
}

// ---------------- emb = yK + cbeta; log_softmax; write both outputs ----------------
__global__ __launch_bounds__(256) void final_kernel(const float* __restrict__ yKf,
                                                    const float* __restrict__ cbeta,
                                                    float* __restrict__ out_ls,
                                                    float* __restrict__ out_emb) {
    const int lane = threadIdx.x & 63;
    const int wv   = threadIdx.x >> 6;
    const int node = blockIdx.x * 4 + wv;        // 25000 * 4 = 100000 exactly

    float e = 0.0f;
    if (lane < OUT_DIM) e = yKf[(size_t)node * PDIM + lane] + cbeta[lane];
    float ev = (lane < OUT_DIM) ? e : -INFINITY;
    float m = ev;
#pragma unroll
    for (int off = 32; off > 0; off >>= 1) m = fmaxf(m, __shfl_xor(m, off, 64));
    float p = (lane < OUT_DIM) ? expf(ev - m) : 0.0f;
    float s = p;
#pragma unroll
    for (int off = 32; off > 0; off >>= 1) s += __shfl_xor(s, off, 64);
    if (lane < OUT_DIM) {
        float ls = ev - m - logf(s);
        out_ls[(size_t)node * OUT_DIM + lane] = ls;
        out_emb[(size_t)node * OUT_DIM + lane] = e;
    }
}

// ---------------- launch ----------------

extern "C" void kernel_launch(void* const* d_in, const int* in_sizes, int n_in,
                              void* d_out, int out_size, void* d_ws, size_t ws_size,
                              hipStream_t stream) {
    const float* x     = (const float*)d_in[0];
    const int*   ei    = (const int*)d_in[1];     // [2, E] int32
    const float* W1    = (const float*)d_in[2];
    const float* b1    = (const float*)d_in[3];
    const float* gamma = (const float*)d_in[4];
    const float* beta  = (const float*)d_in[5];
    const float* mean  = (const float*)d_in[6];
    const float* var   = (const float*)d_in[7];
    const float* W2    = (const float*)d_in[8];
    const float* b2    = (const float*)d_in[9];

    char* ws = (char*)d_ws;
    size_t off = 0;
    auto alloc = [&](size_t bytes) { char* p = ws + off; off += (bytes + 255) & ~(size_t)255; return p; };

    int2*     ew     = (int2*)    alloc((size_t)N_EDGES * 8);          // 25.6 MB
    float*    y0f    = (float*)   alloc((size_t)N_NODES * PDIM * 4);   // 19.2 MB
    float*    yKf    = (float*)   alloc((size_t)N_NODES * PDIM * 4);   // 19.2 MB
    unsigned* y0b    = (unsigned*)alloc((size_t)N_NODES * (PDIM / 2) * 4);  // 9.6 MB
    unsigned* ya     = (unsigned*)alloc((size_t)N_NODES * (PDIM / 2) * 4);
    unsigned* yb     = (unsigned*)alloc((size_t)N_NODES * (PDIM / 2) * 4);
    float*    Wc     = (float*)   alloc((size_t)IN_DIM * PDIM * 4);    // 96 KB
    float*    W2p    = (float*)   alloc(64 * OUT_DIM * 4);
    float*    c1     = (float*)   alloc(PDIM * 4);
    float*    cbeta  = (float*)   alloc(OUT_DIM * 4);
    int*      cnt    = (int*)     alloc(N_NODES * 4);
    float*    dinv   = (float*)   alloc(N_NODES * 4);
    int*      rowptr = (int*)     alloc((N_NODES + 1) * 4);
    int*      cursor = (int*)     alloc(N_NODES * 4);
    int*      psum   = (int*)     alloc(1600 * 4);
    int*      pexcl  = (int*)     alloc(1600 * 4);

    float* out_ls  = (float*)d_out;
    float* out_emb = (float*)d_out + (size_t)N_NODES * OUT_DIM;

    const int NB_N = (N_NODES + 255) / 256;   // 391
    const int NB_E = (N_EDGES + 255) / 256;   // 12500

    zero_cnt_kernel<<<NB_N, 256, 0, stream>>>(cnt);
    hist_kernel<<<NB_E, 256, 0, stream>>>(ei, cnt);
    reduce_kernel<<<NB_N, 256, 0, stream>>>(cnt, psum);
    scanp_kernel<<<1, 512, 0, stream>>>(psum, pexcl, NB_N);
    apply_kernel<<<NB_N, 256, 0, stream>>>(cnt, pexcl, rowptr, cursor, dinv);
    fill_kernel<<<NB_E, 256, 0, stream>>>(ei, dinv, cursor, ew);

    prep_kernel<<<1, 256, 0, stream>>>(W2, gamma, beta, mean, var, b1, b2, W2p, c1, cbeta);
    wc_kernel<<<(IN_DIM * PDIM + 255) / 256, 256, 0, stream>>>(W1, W2p, Wc);
    lin1_kernel<<<(N_NODES + L1_M - 1) / L1_M, 256, 0, stream>>>(x, Wc, c1, y0f, y0b);

    // K=10 steps: y0b -> ya -> yb -> ya -> ... ; last step writes fp32 yKf
    const unsigned* cur = y0b;
    unsigned* nxt = ya;
    unsigned* buf[2] = {ya, yb};
    for (int k = 0; k < K_ITERS - 1; ++k) {
        appnp40_kernel<false><<<N_NODES / 16, 256, 0, stream>>>(rowptr, ew, dinv, cur,
                                                                y0f, nxt, nullptr);
        cur = nxt;
        nxt = buf[(k + 1) & 1];
    }
    appnp40_kernel<true><<<N_NODES / 16, 256, 0, stream>>>(rowptr, ew, dinv, cur,
                                                           y0f, nullptr, yKf);

    final_kernel<<<N_NODES / 4, 256, 0, stream>>>(yKf, cbeta, out_ls, out_emb);
}

// Round 5
// 1327.305 us; speedup vs baseline: 1.9140x; 1.1314x over previous
//
#include <hip/hip_runtime.h>
#include <math.h>

#define N_NODES 100000
#define N_EDGES 3200000
#define IN_DIM  500
#define HID     64
#define OUT_DIM 40
#define K_ITERS 10
#define ALPHA   0.1f
#define BN_EPS  1e-5f

#define PDIM 48        // padded propagation dim
#define NBUCK 782      // ceil(100000/128), bucket = dest >> 7
#define TILE_A 8192    // edges per bucketA block

// ---------------- bf16 helpers ----------------
__device__ __forceinline__ void unpack4(uint2 v, float f[4]) {
    f[0] = __uint_as_float(v.x << 16);
    f[1] = __uint_as_float(v.x & 0xffff0000u);
    f[2] = __uint_as_float(v.y << 16);
    f[3] = __uint_as_float(v.y & 0xffff0000u);
}
__device__ __forceinline__ unsigned pack2(float a, float b) {   // RNE bf16 pair
    unsigned ua = __float_as_uint(a);
    unsigned ub = __float_as_uint(b);
    ua += ((ua >> 16) & 1u) + 0x7fffu;
    ub += ((ub >> 16) & 1u) + 0x7fffu;
    return (ua >> 16) | (ub & 0xffff0000u);
}
// packed edge: low 17 bits = src idx, high 15 bits = weight (f32 bits >> 16, sign 0)
__device__ __forceinline__ float edge_w(unsigned e) {
    return __uint_as_float((e >> 17) << 16);
}
__device__ __forceinline__ void fma4(float4& acc, float wgt, const float f[4]) {
    acc.x = fmaf(wgt, f[0], acc.x);
    acc.y = fmaf(wgt, f[1], acc.y);
    acc.z = fmaf(wgt, f[2], acc.z);
    acc.w = fmaf(wgt, f[3], acc.w);
}

// ---------------- degree histogram + scan ----------------

__global__ void zero_cnt_kernel(int* __restrict__ cnt) {
    int i = blockIdx.x * 256 + threadIdx.x;
    if (i < N_NODES) cnt[i] = 0;
}

__global__ void hist_kernel(const int* __restrict__ ei, int* __restrict__ cnt) {
    int e = blockIdx.x * 256 + threadIdx.x;
    if (e < N_EDGES) atomicAdd(&cnt[ei[N_EDGES + e]], 1);  // col = ei[1][e]
}

__global__ void reduce_kernel(const int* __restrict__ cnt, int* __restrict__ psum) {
    __shared__ int s[256];
    int i = blockIdx.x * 256 + threadIdx.x;
    int v = (i < N_NODES) ? cnt[i] : 0;
    s[threadIdx.x] = v;
    __syncthreads();
    for (int off = 128; off > 0; off >>= 1) {
        if (threadIdx.x < (unsigned)off) s[threadIdx.x] += s[threadIdx.x + off];
        __syncthreads();
    }
    if (threadIdx.x == 0) psum[blockIdx.x] = s[0];
}

__global__ void scanp_kernel(const int* __restrict__ psum, int* __restrict__ pexcl,
                             int nparts) {
    __shared__ int s[512];
    int t = threadIdx.x;
    int v = (t < nparts) ? psum[t] : 0;
    s[t] = v;
    __syncthreads();
    for (int off = 1; off < 512; off <<= 1) {
        int tv = (t >= off) ? s[t - off] : 0;
        __syncthreads();
        s[t] += tv;
        __syncthreads();
    }
    if (t < nparts) pexcl[t] = s[t] - v;
}

__global__ void apply_kernel(const int* __restrict__ cnt, const int* __restrict__ pexcl,
                             int* __restrict__ rowptr, float* __restrict__ dinv) {
    __shared__ int s[256];
    int t = threadIdx.x;
    int i = blockIdx.x * 256 + t;
    int v = (i < N_NODES) ? cnt[i] : 0;
    s[t] = v;
    __syncthreads();
    for (int off = 1; off < 256; off <<= 1) {
        int tv = (t >= off) ? s[t - off] : 0;
        __syncthreads();
        s[t] += tv;
        __syncthreads();
    }
    if (i < N_NODES) {
        int excl = pexcl[blockIdx.x] + s[t] - v;
        rowptr[i] = excl;
        dinv[i] = rsqrtf((float)(v + 1));        // +1 self-loop; always > 0
        if (i == N_NODES - 1) rowptr[N_NODES] = excl + v;
    }
}

// ---------------- bucketed two-phase fill ----------------

__global__ void bcur_init_kernel(const int* __restrict__ rowptr, int* __restrict__ bcursor) {
    int i = blockIdx.x * 256 + threadIdx.x;
    if (i < NBUCK) bcursor[i] = rowptr[i << 7];
}

// Phase A: partition edges into 782 dest-buckets; payload = src(17b) | c_local(7b)
__global__ __launch_bounds__(256) void bucketA_kernel(const int* __restrict__ ei,
                                                      int* __restrict__ bcursor,
                                                      unsigned* __restrict__ ebuf) {
    __shared__ int cnt[NBUCK];
    __shared__ int gbase[NBUCK];
    for (int i = threadIdx.x; i < NBUCK; i += 256) cnt[i] = 0;
    __syncthreads();
    const int e0 = blockIdx.x * TILE_A;
    const int e1 = (e0 + TILE_A < N_EDGES) ? e0 + TILE_A : N_EDGES;
    for (int e = e0 + threadIdx.x; e < e1; e += 256)
        atomicAdd(&cnt[ei[N_EDGES + e] >> 7], 1);
    __syncthreads();
    for (int i = threadIdx.x; i < NBUCK; i += 256) {
        int n = cnt[i];
        gbase[i] = (n > 0) ? atomicAdd(&bcursor[i], n) : 0;
        cnt[i] = 0;     // reuse as rank counter
    }
    __syncthreads();
    for (int e = e0 + threadIdx.x; e < e1; e += 256) {
        int r = ei[e];
        int c = ei[N_EDGES + e];
        int b = c >> 7;
        int rank = atomicAdd(&cnt[b], 1);
        ebuf[gbase[b] + rank] = (unsigned)r | ((unsigned)(c & 127) << 17);
    }
}

// Phase B: one block per bucket; node cursors in LDS; write packed (src|w) CSR
__global__ __launch_bounds__(256) void bucketB_kernel(const unsigned* __restrict__ ebuf,
                                                      const int* __restrict__ rowptr,
                                                      const float* __restrict__ dinv,
                                                      unsigned* __restrict__ ew) {
    __shared__ int lcur[128];
    __shared__ float ldinv[128];
    const int base = blockIdx.x << 7;
    const int nn = (N_NODES - base < 128) ? (N_NODES - base) : 128;
    if (threadIdx.x < (unsigned)nn) {
        lcur[threadIdx.x] = rowptr[base + threadIdx.x];
        ldinv[threadIdx.x] = dinv[base + threadIdx.x];
    }
    __syncthreads();
    const int s0 = rowptr[base];
    const int hi = (base + 128 < N_NODES) ? base + 128 : N_NODES;
    const int s1 = rowptr[hi];
    for (int p = s0 + threadIdx.x; p < s1; p += 256) {
        unsigned v = ebuf[p];
        int r = v & 0x1ffff;
        int cl = v >> 17;
        int pos = atomicAdd(&lcur[cl], 1);
        float w = dinv[r] * ldinv[cl];
        unsigned f = __float_as_uint(w) + 0x8000u;   // round-half-up to e8m7
        ew[pos] = (unsigned)r | ((f >> 16) << 17);
    }
}

// ---------------- fold BN+W2 into propagation space ----------------
__global__ void prep_kernel(const float* __restrict__ W2, const float* __restrict__ gamma,
                            const float* __restrict__ beta, const float* __restrict__ mean,
                            const float* __restrict__ var, const float* __restrict__ b1,
                            const float* __restrict__ b2, float* __restrict__ W2p,
                            float* __restrict__ c1, float* __restrict__ cbeta) {
    __shared__ float sc[64];
    __shared__ float sd[64];
    int t = threadIdx.x;
    if (t < 64) {
        float s = rsqrtf(var[t] + BN_EPS) * gamma[t];
        sc[t] = s;
        sd[t] = beta[t] - mean[t] * s;
    }
    __syncthreads();
    for (int i = t; i < 64 * OUT_DIM; i += 256) {
        int f = i / OUT_DIM;
        W2p[i] = sc[f] * W2[i];
    }
    if (t < PDIM) {
        if (t < OUT_DIM) {
            float acb = b2[t], ac1 = 0.f;
            for (int f = 0; f < 64; ++f) {
                float w2 = W2[f * OUT_DIM + t];
                acb = fmaf(sd[f], w2, acb);
                ac1 = fmaf(b1[f] * sc[f], w2, ac1);
            }
            cbeta[t] = acb;
            c1[t] = ac1;
        } else {
            c1[t] = 0.f;
        }
    }
}

__global__ __launch_bounds__(256) void wc_kernel(const float* __restrict__ W1,
                                                 const float* __restrict__ W2p,
                                                 float* __restrict__ Wc) {
    __shared__ float w2s[64 * OUT_DIM];
    for (int i = threadIdx.x; i < 64 * OUT_DIM; i += 256) w2s[i] = W2p[i];
    __syncthreads();
    int idx = blockIdx.x * 256 + threadIdx.x;
    if (idx >= IN_DIM * PDIM) return;
    int k = idx / PDIM, o = idx % PDIM;
    float a = 0.f;
    if (o < OUT_DIM) {
        const float* w1r = W1 + (size_t)k * HID;
#pragma unroll 8
        for (int f = 0; f < 64; ++f) a = fmaf(w1r[f], w2s[f * OUT_DIM + o], a);
    }
    Wc[idx] = a;
}

// ---------------- y0 = x @ Wc + c1 ----------------
#define L1_M  128
#define L1_KC 20
#define L1_PITCH 132
__global__ __launch_bounds__(256) void lin1_kernel(const float* __restrict__ x,
                                                   const float* __restrict__ Wc,
                                                   const float* __restrict__ c1,
                                                   float* __restrict__ y0f,
                                                   unsigned* __restrict__ y0b) {
    __shared__ float xsT[L1_KC * L1_PITCH];
    __shared__ float wcs[L1_KC * PDIM];

    const int t = threadIdx.x;
    const int ng = t & 31;
    const int og = t >> 5;
    const int nbase = blockIdx.x * L1_M;

    const int srow = t >> 1;
    const int skb  = (t & 1) * 10;
    const int gsrc = nbase + srow;
    const int gcl  = (gsrc < N_NODES) ? gsrc : (N_NODES - 1);
    const float* xrow = x + (size_t)gcl * IN_DIM;

    float acc[4][6];
#pragma unroll
    for (int i = 0; i < 4; ++i)
#pragma unroll
        for (int j = 0; j < 6; ++j) acc[i][j] = 0.0f;

    for (int k0 = 0; k0 < IN_DIM; k0 += L1_KC) {
        __syncthreads();
#pragma unroll
        for (int u = 0; u < 5; ++u) {
            const float2 xv = *(const float2*)(xrow + k0 + skb + 2 * u);
            xsT[(skb + 2 * u) * L1_PITCH + srow]     = xv.x;
            xsT[(skb + 2 * u + 1) * L1_PITCH + srow] = xv.y;
        }
        for (int i = t; i < L1_KC * PDIM; i += 256) wcs[i] = Wc[(size_t)k0 * PDIM + i];
        __syncthreads();

#pragma unroll 4
        for (int k = 0; k < L1_KC; ++k) {
            const float4 xv = *(const float4*)&xsT[k * L1_PITCH + ng * 4];
            float w[6];
#pragma unroll
            for (int j = 0; j < 6; ++j) w[j] = wcs[k * PDIM + og * 6 + j];
            const float xr[4] = {xv.x, xv.y, xv.z, xv.w};
#pragma unroll
            for (int i = 0; i < 4; ++i)
#pragma unroll
                for (int j = 0; j < 6; ++j)
                    acc[i][j] = fmaf(xr[i], w[j], acc[i][j]);
        }
    }

    float cc[6];
#pragma unroll
    for (int j = 0; j < 6; ++j) cc[j] = c1[og * 6 + j];
#pragma unroll
    for (int i = 0; i < 4; ++i) {
        const int n = nbase + ng * 4 + i;
        if (n < N_NODES) {
            float o[6];
#pragma unroll
            for (int j = 0; j < 6; ++j) o[j] = acc[i][j] + cc[j];
            float* yf = y0f + (size_t)n * PDIM + og * 6;
            *(float2*)(yf)     = make_float2(o[0], o[1]);
            *(float2*)(yf + 2) = make_float2(o[2], o[3]);
            *(float2*)(yf + 4) = make_float2(o[4], o[5]);
            unsigned* yb = y0b + (size_t)n * (PDIM / 2) + og * 3;
            yb[0] = pack2(o[0], o[1]);
            yb[1] = pack2(o[2], o[3]);
            yb[2] = pack2(o[4], o[5]);
        }
    }
}

// ---------------- APPNP step (40-dim, bf16 gather, fp32 accumulate) ----------------
template <bool LAST>
__global__ __launch_bounds__(256) void appnp40_kernel(const int* __restrict__ rowptr,
                                                      const unsigned* __restrict__ ew,
                                                      const float* __restrict__ dinv,
                                                      const unsigned* __restrict__ yin,
                                                      const float* __restrict__ h,
                                                      unsigned* __restrict__ yout,
                                                      float* __restrict__ yKf) {
    const int sub   = threadIdx.x >> 4;
    const int lane4 = threadIdx.x & 15;
    const int node  = blockIdx.x * 16 + sub;     // 6250 * 16 = 100000 exactly
    const bool act  = lane4 < 10;

    const int beg = rowptr[node];
    const int end = rowptr[node + 1];
    float4 acc = make_float4(0.f, 0.f, 0.f, 0.f);
    int p = beg;
    for (; p + 3 < end; p += 4) {
        const unsigned e0 = ew[p], e1 = ew[p + 1], e2 = ew[p + 2], e3 = ew[p + 3];
        if (act) {
            const uint2 v0 = *(const uint2*)(yin + (size_t)(e0 & 0x1ffff) * (PDIM / 2) + lane4 * 2);
            const uint2 v1 = *(const uint2*)(yin + (size_t)(e1 & 0x1ffff) * (PDIM / 2) + lane4 * 2);
            const uint2 v2 = *(const uint2*)(yin + (size_t)(e2 & 0x1ffff) * (PDIM / 2) + lane4 * 2);
            const uint2 v3 = *(const uint2*)(yin + (size_t)(e3 & 0x1ffff) * (PDIM / 2) + lane4 * 2);
            float f0[4], f1[4], f2[4], f3[4];
            unpack4(v0, f0); unpack4(v1, f1); unpack4(v2, f2); unpack4(v3, f3);
            fma4(acc, edge_w(e0), f0);
            fma4(acc, edge_w(e1), f1);
            fma4(acc, edge_w(e2), f2);
            fma4(acc, edge_w(e3), f3);
        }
    }
    for (; p < end; ++p) {
        const unsigned e0 = ew[p];
        if (act) {
            const uint2 v0 = *(const uint2*)(yin + (size_t)(e0 & 0x1ffff) * (PDIM / 2) + lane4 * 2);
            float f0[4];
            unpack4(v0, f0);
            fma4(acc, edge_w(e0), f0);
        }
    }
    if (act) {
        const float di = dinv[node];
        const float selfw = di * di;
        const uint2 vs = *(const uint2*)(yin + (size_t)node * (PDIM / 2) + lane4 * 2);
        float fs[4];
        unpack4(vs, fs);
        const float4 hh = *(const float4*)(h + (size_t)node * PDIM + lane4 * 4);
        float4 o;
        o.x = (1.0f - ALPHA) * fmaf(selfw, fs[0], acc.x) + ALPHA * hh.x;
        o.y = (1.0f - ALPHA) * fmaf(selfw, fs[1], acc.y) + ALPHA * hh.y;
        o.z = (1.0f - ALPHA) * fmaf(selfw, fs[2], acc.z) + ALPHA * hh.z;
        o.w = (1.0f - ALPHA) * fmaf(selfw, fs[3], acc.w) + ALPHA * hh.w;
        if (LAST) {
            *(float4*)(yKf + (size_t)node * PDIM + lane4 * 4) = o;
        } else {
            uint2 w;
            w.x = pack2(o.x, o.y);
            w.y = pack2(o.z, o.w);
            *(uint2*)(yout + (size_t)node * (PDIM / 2) + lane4 * 2) = w;
        }
    }
}

// ---------------- emb = yK + cbeta; log_softmax ----------------
__global__ __launch_bounds__(256) void final_kernel(const float* __restrict__ yKf,
                                                    const float* __restrict__ cbeta,
                                                    float* __restrict__ out_ls,
                                                    float* __restrict__ out_emb) {
    const int lane = threadIdx.x & 63;
    const int wv   = threadIdx.x >> 6;
    const int node = blockIdx.x * 4 + wv;

    float e = 0.0f;
    if (lane < OUT_DIM) e = yKf[(size_t)node * PDIM + lane] + cbeta[lane];
    float ev = (lane < OUT_DIM) ? e : -INFINITY;
    float m = ev;
#pragma unroll
    for (int off = 32; off > 0; off >>= 1) m = fmaxf(m, __shfl_xor(m, off, 64));
    float p = (lane < OUT_DIM) ? expf(ev - m) : 0.0f;
    float s = p;
#pragma unroll
    for (int off = 32; off > 0; off >>= 1) s += __shfl_xor(s, off, 64);
    if (lane < OUT_DIM) {
        float ls = ev - m - logf(s);
        out_ls[(size_t)node * OUT_DIM + lane] = ls;
        out_emb[(size_t)node * OUT_DIM + lane] = e;
    }
}

// ---------------- launch ----------------

extern "C" void kernel_launch(void* const* d_in, const int* in_sizes, int n_in,
                              void* d_out, int out_size, void* d_ws, size_t ws_size,
                              hipStream_t stream) {
    const float* x     = (const float*)d_in[0];
    const int*   ei    = (const int*)d_in[1];
    const float* W1    = (const float*)d_in[2];
    const float* b1    = (const float*)d_in[3];
    const float* gamma = (const float*)d_in[4];
    const float* beta  = (const float*)d_in[5];
    const float* mean  = (const float*)d_in[6];
    const float* var   = (const float*)d_in[7];
    const float* W2    = (const float*)d_in[8];
    const float* b2    = (const float*)d_in[9];

    char* ws = (char*)d_ws;
    size_t off = 0;
    auto alloc = [&](size_t bytes) { char* p = ws + off; off += (bytes + 255) & ~(size_t)255; return p; };

    unsigned* ew     = (unsigned*)alloc((size_t)N_EDGES * 4);          // 12.8 MB
    unsigned* ebuf   = (unsigned*)alloc((size_t)N_EDGES * 4);          // 12.8 MB
    float*    y0f    = (float*)   alloc((size_t)N_NODES * PDIM * 4);   // 19.2 MB
    float*    yKf    = (float*)   alloc((size_t)N_NODES * PDIM * 4);   // 19.2 MB
    unsigned* y0b    = (unsigned*)alloc((size_t)N_NODES * (PDIM / 2) * 4);  // 9.6 MB
    unsigned* ya     = (unsigned*)alloc((size_t)N_NODES * (PDIM / 2) * 4);
    unsigned* yb     = (unsigned*)alloc((size_t)N_NODES * (PDIM / 2) * 4);
    float*    Wc     = (float*)   alloc((size_t)IN_DIM * PDIM * 4);
    float*    W2p    = (float*)   alloc(64 * OUT_DIM * 4);
    float*    c1     = (float*)   alloc(PDIM * 4);
    float*    cbeta  = (float*)   alloc(OUT_DIM * 4);
    int*      cnt    = (int*)     alloc(N_NODES * 4);
    float*    dinv   = (float*)   alloc(N_NODES * 4);
    int*      rowptr = (int*)     alloc((N_NODES + 1) * 4);
    int*      bcursor= (int*)     alloc(NBUCK * 4);
    int*      psum   = (int*)     alloc(1600 * 4);
    int*      pexcl  = (int*)     alloc(1600 * 4);

    float* out_ls  = (float*)d_out;
    float* out_emb = (float*)d_out + (size_t)N_NODES * OUT_DIM;

    const int NB_N = (N_NODES + 255) / 256;   // 391
    const int NB_E = (N_EDGES + 255) / 256;   // 12500
    const int NB_A = (N_EDGES + TILE_A - 1) / TILE_A;  // 391

    zero_cnt_kernel<<<NB_N, 256, 0, stream>>>(cnt);
    hist_kernel<<<NB_E, 256, 0, stream>>>(ei, cnt);
    reduce_kernel<<<NB_N, 256, 0, stream>>>(cnt, psum);
    scanp_kernel<<<1, 512, 0, stream>>>(psum, pexcl, NB_N);
    apply_kernel<<<NB_N, 256, 0, stream>>>(cnt, pexcl, rowptr, dinv);
    bcur_init_kernel<<<(NBUCK + 255) / 256, 256, 0, stream>>>(rowptr, bcursor);
    bucketA_kernel<<<NB_A, 256, 0, stream>>>(ei, bcursor, ebuf);
    bucketB_kernel<<<NBUCK, 256, 0, stream>>>(ebuf, rowptr, dinv, ew);

    prep_kernel<<<1, 256, 0, stream>>>(W2, gamma, beta, mean, var, b1, b2, W2p, c1, cbeta);
    wc_kernel<<<(IN_DIM * PDIM + 255) / 256, 256, 0, stream>>>(W1, W2p, Wc);
    lin1_kernel<<<(N_NODES + L1_M - 1) / L1_M, 256, 0, stream>>>(x, Wc, c1, y0f, y0b);

    const unsigned* cur = y0b;
    unsigned* nxt = ya;
    unsigned* buf[2] = {ya, yb};
    for (int k = 0; k < K_ITERS - 1; ++k) {
        appnp40_kernel<false><<<N_NODES / 16, 256, 0, stream>>>(rowptr, ew, dinv, cur,
                                                                y0f, nxt, nullptr);
        cur = nxt;
        nxt = buf[(k + 1) & 1];
    }
    appnp40_kernel<true><<<N_NODES / 16, 256, 0, stream>>>(rowptr, ew, dinv, cur,
                                                           y0f, nullptr, yKf);

    final_kernel<<<N_NODES / 4, 256, 0, stream>>>(yKf, cbeta, out_ls, out_emb);
}